// Round 7
// baseline (1399.086 us; speedup 1.0000x reference)
//
#include <hip/hip_runtime.h>
#include <stdint.h>

// ---------------------------------------------------------------------------
// TContrastive: GRACE InfoNCE loss.
//   loss_view = (1/2N) sum_i log(S_i - e^2) - (2/N) sum_i g12_i
// where S = row sums of exp(2 * M M^T), M = [n1; n2] row-normalized (16384x1024).
// Heavy GEMMs in bf16 MFMA, fp32 accumulate. tau = 0.5.
// R1: Gram symmetry — triangle tiles only; off-diag adds row+col exp-sums.
// R2-R6 lessons:
//   - SQ_LDS_BANK_CONFLICT (2.556e7) is bit-invariant across 4 layouts = it is
//     the global_load_lds DMA-WRITE port (2.13e6 wave-writes x 12 cyc), not
//     ds_read conflicts. Read-swizzle surgery was aimed at the wrong operand.
//   - XCD chunk swizzle HURT (FETCH 314->488MB): default mapping already good.
//   - 4-phase/8-phase ports regressed; 1-barrier ring-4 (R4) best: 412us.
// R7: three bounded changes on top of R4:
//   (1) gram MFMA shape 16x16x32 -> 32x32x16: same FLOP/reads, half the MFMA
//       issues, 8.07 vs 9.7 cyc per 32k FLOP (-17% matrix pipe).
//   (2) both view-grams merged into ONE 4160-block dispatch (Hc lives in the
//       freed Z buffer) - pays the 8.125-blocks/CU dispatch tail once.
//   (3) XCD swizzle reverted; stage gloads issued before ds_reads.
// ---------------------------------------------------------------------------

typedef unsigned short u16;
typedef __attribute__((ext_vector_type(8))) __bf16 bf16x8;
typedef __attribute__((ext_vector_type(4))) float f32x4;
typedef __attribute__((ext_vector_type(16))) float f32x16;

#define NS 8192       // samples per view half
#define DD 1024       // feature dim

__device__ __forceinline__ float bf2f(u16 u) {
    union { uint32_t i; float f; } v; v.i = ((uint32_t)u) << 16; return v.f;
}
__device__ __forceinline__ u16 f2bf(float f) {
    union { float f; uint32_t i; } v; v.f = f;
    return (u16)((v.i + 0x7FFFu + ((v.i >> 16) & 1u)) >> 16);   // RNE
}

// async global->LDS, 16B per lane. LDS dest must be wave-uniform-base + lane*16.
__device__ __forceinline__ void gload16(const u16* g, u16* l) {
    __builtin_amdgcn_global_load_lds(
        (__attribute__((address_space(1))) void*)(uintptr_t)(g),
        (__attribute__((address_space(3))) void*)(uintptr_t)(l), 16, 0, 0);
}

// ---------------- elementwise conversion kernels ----------------

__global__ __launch_bounds__(256) void conv_f2bf(const float* __restrict__ src,
                                                 u16* __restrict__ dst) {
    int i = (blockIdx.x * 256 + threadIdx.x) * 4;
    float4 v = *(const float4*)(src + i);
    ushort4 o;
    o.x = f2bf(v.x); o.y = f2bf(v.y); o.z = f2bf(v.z); o.w = f2bf(v.w);
    *(ushort4*)(dst + i) = o;
}

// Z = bf16([ta; tb]) row view (16384x1024), 16384 blocks
__global__ __launch_bounds__(256) void conv_cat(const float* __restrict__ a,
                                                const float* __restrict__ b,
                                                u16* __restrict__ Z) {
    size_t i = (size_t)(blockIdx.x * 256 + threadIdx.x) * 4;
    const size_t half = (size_t)NS * DD;
    const float* s = (i < half) ? (a + i) : (b + (i - half));
    float4 v = *(const float4*)s;
    ushort4 o;
    o.x = f2bf(v.x); o.y = f2bf(v.y); o.z = f2bf(v.z); o.w = f2bf(v.w);
    *(ushort4*)(Z + i) = o;
}

// column view: Z[i, b*32+a] = src[i, a*32+b]  (per-row 32x32 transpose)
__global__ __launch_bounds__(256) void conv_col(const float* __restrict__ a,
                                                const float* __restrict__ b,
                                                u16* __restrict__ Z) {
    size_t i = (size_t)(blockIdx.x * 256 + threadIdx.x) * 4;
    const size_t half = (size_t)NS * DD;
    const float* src; size_t o;
    if (i < half) { src = a; o = i; } else { src = b; o = i - half; }
    size_t row = o >> 10;
    int j = (int)(o & 1023);
    int aI = j & 31, bI = j >> 5;      // j = b*32 + a
    const float* rp = src + (row << 10);
    ushort4 ov;
    ov.x = f2bf(rp[aI * 32 + bI]);
    ov.y = f2bf(rp[(aI + 1) * 32 + bI]);
    ov.z = f2bf(rp[(aI + 2) * 32 + bI]);
    ov.w = f2bf(rp[(aI + 3) * 32 + bI]);
    *(ushort4*)(Z + i) = ov;
}

// ---------------- fc GEMM: C[m,n] = sum_k A[m,k] * B[n,k] (128^2 tile path)
// MODE 0: out = bf16(elu(C + bias))      (fc_a)
// MODE 1: out = bf16(C + bias)           (fc_b)
template <int MODE>
__global__ __launch_bounds__(256) void gemm_bt(const u16* A, const u16* B,
                                               const float* __restrict__ bias,
                                               u16* __restrict__ out) {
    __shared__ alignas(16) u16 As[128 * 32];
    __shared__ alignas(16) u16 Bs[128 * 32];
    const int tid = threadIdx.x;

    const int tm = blockIdx.y, tn = blockIdx.x;
    const size_t tileM = (size_t)tm * 128;
    const size_t tileN = (size_t)tn * 128;

    const int csw = ((tid & 3) ^ ((tid >> 4) & 3)) * 8;
    const u16* gA0 = A + (tileM + (tid >> 2)) * DD + csw;
    const u16* gA1 = gA0 + (size_t)64 * DD;
    const u16* gB0 = B + (tileN + (tid >> 2)) * DD + csw;
    const u16* gB1 = gB0 + (size_t)64 * DD;
    u16* lA0 = &As[tid * 8]; u16* lA1 = lA0 + 2048;
    u16* lB0 = &Bs[tid * 8]; u16* lB1 = lB0 + 2048;

    const int lane = tid & 63;
    const int wv = tid >> 6;
    const int wr = (wv >> 1) << 6;
    const int wc = (wv & 1) << 6;
    const int lr = lane & 15;
    const int lh = lane >> 4;
    const int sw = lh ^ ((lr >> 2) & 3);

    const u16* aBase = &As[(wr + lr) * 32 + sw * 8];
    const u16* bBase = &Bs[(wc + lr) * 32 + sw * 8];

    f32x4 acc[4][4];
#pragma unroll
    for (int i = 0; i < 4; i++)
#pragma unroll
        for (int j = 0; j < 4; j++) acc[i][j] = (f32x4)0.0f;

    for (int k0 = 0; k0 < DD; k0 += 32) {
        gload16(gA0 + k0, lA0);
        gload16(gA1 + k0, lA1);
        gload16(gB0 + k0, lB0);
        gload16(gB1 + k0, lB1);
        __syncthreads();
        bf16x8 af[4], bfr[4];
#pragma unroll
        for (int rt = 0; rt < 4; rt++) af[rt] = *(const bf16x8*)(aBase + rt * 512);
#pragma unroll
        for (int ct = 0; ct < 4; ct++) bfr[ct] = *(const bf16x8*)(bBase + ct * 512);
#pragma unroll
        for (int rt = 0; rt < 4; rt++)
#pragma unroll
            for (int ct = 0; ct < 4; ct++)
                acc[rt][ct] = __builtin_amdgcn_mfma_f32_16x16x32_bf16(
                    af[rt], bfr[ct], acc[rt][ct], 0, 0, 0);
        __syncthreads();
    }

    float bcol[4];
#pragma unroll
    for (int ct = 0; ct < 4; ct++) bcol[ct] = bias[tileN + wc + ct * 16 + lr];
#pragma unroll
    for (int rt = 0; rt < 4; rt++) {
#pragma unroll
        for (int r = 0; r < 4; r++) {
            size_t row = tileM + wr + rt * 16 + lh * 4 + r;
            u16* orow = out + row * DD + tileN + wc + lr;
#pragma unroll
            for (int ct = 0; ct < 4; ct++) {
                float v = acc[rt][ct][r] + bcol[ct];
                if (MODE == 0) v = v > 0.0f ? v : expm1f(v);
                orow[ct * 16] = f2bf(v);
            }
        }
    }
}

// ---------------- Combined Gram kernel: both views in one dispatch ------
// 256^2 tiles, 8 waves, BK=32, 4-deep LDS ring, one barrier per K-tile,
// MFMA shape 32x32x16 (half the issues of 16x16x32 for same FLOP).
// Grid dim3(65, 64): y<32 = row view (Hr->Sbase), y>=32 = col view
// (Hc->Sbase+2NS). Per view: 2080-block triangle of the 64x64 tile grid.
__global__ __launch_bounds__(512, 2) void gram256(const u16* __restrict__ Hr,
                                                  const u16* __restrict__ Hc,
                                                  float* __restrict__ Sbase) {
    __shared__ alignas(16) u16 LA[4][256 * 32];
    __shared__ alignas(16) u16 LB[4][256 * 32];
    const int tid = threadIdx.x;

    const int view = (int)blockIdx.y >> 5;
    const u16* H = view ? Hc : Hr;
    float* S = Sbase + view * 2 * NS;
    const int x = blockIdx.x, y = (int)blockIdx.y & 31;
    int tm, tn;
    if (y + x < 64) { tm = y;      tn = y + x; }
    else            { tm = 63 - y; tn = x - 1; }

    const size_t rowA = (size_t)tm * 256;
    const size_t rowB = (size_t)tn * 256;

    // staging (identical to R4): LDS dest LINEAR (tid*16B); global source col
    // slot pre-swizzled by (row>>2)&3:  LDS[row][s] = G[row][k0+(s^((row>>2)&3))*8..]
    const int r_lo = tid >> 2;                      // 0..127
    const int csw  = ((tid & 3) ^ ((r_lo >> 2) & 3)) * 8;
    const u16* gA0 = H + (rowA + r_lo) * DD + csw;
    const u16* gA1 = H + (rowA + 128 + r_lo) * DD + csw;
    const u16* gB0 = H + (rowB + r_lo) * DD + csw;
    const u16* gB1 = H + (rowB + 128 + r_lo) * DD + csw;
    const int ldst = tid * 8;                       // u16 offset of chunk

    // MFMA indexing: 8 waves = 2M x 4N; per-wave output 128x64 as 4x2 tiles
    // of 32x32, K-tile 32 = 2 k-steps of 16.
    // A/B frag (32x32x16): row = base + (lane&31), k = (lane>>5)*8 + j.
    // stored slot for global k-slot g at row r: g ^ ((r>>2)&3); wr,wc,mt*32
    // are 0 mod 4 after >>2, so (row>>2)&3 = ((lane&31)>>2)&3.
    const int lane = tid & 63;
    const int wv = tid >> 6;
    const int wr = (wv >> 2) * 128;          // wave row offset: 0 / 128
    const int wc = (wv & 3) * 64;            // wave col offset: 0/64/128/192
    const int c31 = lane & 31;
    const int hi  = lane >> 5;
    const int q4  = (c31 >> 2) & 3;
    const int o0  = (hi ^ q4) * 8;           // kk=0: global slot = hi
    const int o1  = ((hi ^ q4) ^ 2) * 8;     // kk=1: global slot = 2+hi
    const int aBase = (wr + c31) * 32;       // u16 offset of this lane's A row
    const int bBase = (wc + c31) * 32;

    f32x16 acc[4][2];
#pragma unroll
    for (int i = 0; i < 4; ++i)
#pragma unroll
        for (int j = 0; j < 2; ++j) acc[i][j] = (f32x16)0.0f;

    // prologue: stage K-tiles 0,1,2 (12 gloads/thread)
#pragma unroll
    for (int t = 0; t < 3; ++t) {
        const int k0 = t * 32;
        gload16(gA0 + k0, &LA[t][0] + ldst);
        gload16(gA1 + k0, &LA[t][4096] + ldst);
        gload16(gB0 + k0, &LB[t][0] + ldst);
        gload16(gB1 + k0, &LB[t][4096] + ldst);
    }

    // main loop: one barrier per K-tile; stage(t+3) issued FIRST (earliest DMA
    // start), then 12 ds_reads, then 16 MFMA gated by compiler-counted lgkm.
    // vmcnt gate: 4 gloads/tile; tiles t+1,t+2 (8 loads) stay in flight.
    for (int t = 0; t < 32; ++t) {
        if (t < 30)       asm volatile("s_waitcnt vmcnt(8)" ::: "memory");
        else if (t == 30) asm volatile("s_waitcnt vmcnt(4)" ::: "memory");
        else              asm volatile("s_waitcnt vmcnt(0)" ::: "memory");
        __builtin_amdgcn_s_barrier();
        asm volatile("" ::: "memory");

        if (t < 29) {
            const int nbuf = (t + 3) & 3;
            const int k0n = (t + 3) * 32;
            gload16(gA0 + k0n, &LA[nbuf][0] + ldst);
            gload16(gA1 + k0n, &LA[nbuf][4096] + ldst);
            gload16(gB0 + k0n, &LB[nbuf][0] + ldst);
            gload16(gB1 + k0n, &LB[nbuf][4096] + ldst);
        }

        const int buf = t & 3;
        const u16* la = &LA[buf][0];
        const u16* lb = &LB[buf][0];

        bf16x8 aF[4][2], bF[2][2];
#pragma unroll
        for (int nt = 0; nt < 2; ++nt) {
            bF[nt][0] = *(const bf16x8*)(lb + bBase + nt * 1024 + o0);
            bF[nt][1] = *(const bf16x8*)(lb + bBase + nt * 1024 + o1);
        }
#pragma unroll
        for (int mt = 0; mt < 4; ++mt) {
            aF[mt][0] = *(const bf16x8*)(la + aBase + mt * 1024 + o0);
            aF[mt][1] = *(const bf16x8*)(la + aBase + mt * 1024 + o1);
        }

        __builtin_amdgcn_s_setprio(1);
#pragma unroll
        for (int mt = 0; mt < 4; ++mt)
#pragma unroll
            for (int nt = 0; nt < 2; ++nt)
#pragma unroll
                for (int kk = 0; kk < 2; ++kk)
                    acc[mt][nt] = __builtin_amdgcn_mfma_f32_32x32x16_bf16(
                        aF[mt][kk], bF[nt][kk], acc[mt][nt], 0, 0, 0);
        __builtin_amdgcn_s_setprio(0);
    }

    // epilogue: exp + row sums (always) + col sums (off-diag symmetry).
    // 32x32 C layout: col = lane&31, row = (j&3) + 8*(j>>2) + 4*(lane>>5).
    const bool offdiag = (tm != tn);
    float csum[2] = {0.f, 0.f};
#pragma unroll
    for (int mt = 0; mt < 4; ++mt) {
#pragma unroll
        for (int j = 0; j < 16; ++j) {
            float rs = 0.0f;
#pragma unroll
            for (int nt = 0; nt < 2; ++nt) {
                float e = __expf(2.0f * acc[mt][nt][j]);
                rs += e;
                csum[nt] += e;
            }
            rs += __shfl_xor(rs, 1);
            rs += __shfl_xor(rs, 2);
            rs += __shfl_xor(rs, 4);
            rs += __shfl_xor(rs, 8);
            rs += __shfl_xor(rs, 16);
            if (c31 == 0) {
                size_t row = rowA + wr + mt * 32 + (j & 3) + 8 * (j >> 2) + 4 * hi;
                atomicAdd(&S[row], rs);
            }
        }
    }
    if (offdiag) {
#pragma unroll
        for (int nt = 0; nt < 2; ++nt) {
            float cs = csum[nt];
            cs += __shfl_xor(cs, 32);      // merge the two row-halves
            if (hi == 0) {
                size_t col = rowB + wc + nt * 32 + c31;
                atomicAdd(&S[col], cs);
            }
        }
    }
}

// row-normalize bf16 matrix in place (one block per row of 1024)
__global__ __launch_bounds__(256) void normalize_kernel(u16* M) {
    __shared__ float red[4];
    const int tid = threadIdx.x;
    u16* row = M + ((size_t)blockIdx.x << 10);
    ushort4 v = ((const ushort4*)row)[tid];
    float x0 = bf2f(v.x), x1 = bf2f(v.y), x2 = bf2f(v.z), x3 = bf2f(v.w);
    float s = x0 * x0 + x1 * x1 + x2 * x2 + x3 * x3;
#pragma unroll
    for (int m = 1; m < 64; m <<= 1) s += __shfl_xor(s, m);
    if ((tid & 63) == 0) red[tid >> 6] = s;
    __syncthreads();
    float inv = rsqrtf(red[0] + red[1] + red[2] + red[3]);
    ushort4 o;
    o.x = f2bf(x0 * inv); o.y = f2bf(x1 * inv);
    o.z = f2bf(x2 * inv); o.w = f2bf(x3 * inv);
    ((ushort4*)row)[tid] = o;
}

// g12[i] = dot(M[i], M[i+NS])  (one block per i)
__global__ __launch_bounds__(256) void diag_kernel(const u16* M, float* g12) {
    __shared__ float red[4];
    const int tid = threadIdx.x;
    const u16* r1 = M + ((size_t)blockIdx.x << 10);
    const u16* r2 = r1 + ((size_t)NS << 10);
    ushort4 a = ((const ushort4*)r1)[tid];
    ushort4 b = ((const ushort4*)r2)[tid];
    float s = bf2f(a.x) * bf2f(b.x) + bf2f(a.y) * bf2f(b.y) +
              bf2f(a.z) * bf2f(b.z) + bf2f(a.w) * bf2f(b.w);
#pragma unroll
    for (int m = 1; m < 64; m <<= 1) s += __shfl_xor(s, m);
    if ((tid & 63) == 0) red[tid >> 6] = s;
    __syncthreads();
    if (tid == 0) g12[blockIdx.x] = red[0] + red[1] + red[2] + red[3];
}

__global__ __launch_bounds__(256) void final_kernel(const float* Sr, const float* Sc,
                                                    const float* gr, const float* gc,
                                                    const float* w_r1, float* out) {
    __shared__ float red[16];
    const float E2 = 7.389056098930650f;  // exp(1/tau), tau=0.5
    float a = 0.f, b = 0.f, c = 0.f, d = 0.f;
    for (int i = threadIdx.x; i < 2 * NS; i += 256) {
        a += logf(Sr[i] - E2);
        b += logf(Sc[i] - E2);
    }
    for (int i = threadIdx.x; i < NS; i += 256) {
        c += gr[i];
        d += gc[i];
    }
#pragma unroll
    for (int m = 1; m < 64; m <<= 1) {
        a += __shfl_xor(a, m); b += __shfl_xor(b, m);
        c += __shfl_xor(c, m); d += __shfl_xor(d, m);
    }
    int w = threadIdx.x >> 6;
    if ((threadIdx.x & 63) == 0) {
        red[w] = a; red[4 + w] = b; red[8 + w] = c; red[12 + w] = d;
    }
    __syncthreads();
    if (threadIdx.x == 0) {
        a = red[0] + red[1] + red[2] + red[3];
        b = red[4] + red[5] + red[6] + red[7];
        c = red[8] + red[9] + red[10] + red[11];
        d = red[12] + red[13] + red[14] + red[15];
        float lr = a / (2.0f * NS) - 2.0f * c / NS;
        float lc = b / (2.0f * NS) - 2.0f * d / NS;
        float w0 = w_r1[0];
        w0 = fminf(fmaxf(w0, 0.0f), 1.0f);
        out[0] = w0 * lr + (1.0f - w0) * lc;
    }
}

extern "C" void kernel_launch(void* const* d_in, const int* in_sizes, int n_in,
                              void* d_out, int out_size, void* d_ws, size_t ws_size,
                              hipStream_t stream) {
    const float* ta = (const float*)d_in[0];
    const float* tb = (const float*)d_in[1];
    const float* W1 = (const float*)d_in[2];
    const float* b1 = (const float*)d_in[3];
    const float* W2 = (const float*)d_in[4];
    const float* b2 = (const float*)d_in[5];
    const float* W3 = (const float*)d_in[6];
    const float* b3 = (const float*)d_in[7];
    const float* W4 = (const float*)d_in[8];
    const float* b4 = (const float*)d_in[9];
    const float* wr = (const float*)d_in[10];
    float* out = (float*)d_out;

    char* p = (char*)d_ws;
    const size_t MAT = (size_t)2 * NS * DD * sizeof(u16);  // 33.5 MB
    u16* Z = (u16*)p;  p += MAT;    // row-view input; later holds Hc
    u16* T = (u16*)p;  p += MAT;
    u16* H = (u16*)p;  p += MAT;    // Hr
    u16* Wb = (u16*)p; p += (size_t)4 * DD * DD * sizeof(u16);
    float* Sr = (float*)p;  p += 2 * NS * sizeof(float);
    float* Sc = (float*)p;  p += 2 * NS * sizeof(float);
    float* gr = (float*)p;  p += NS * sizeof(float);
    float* gc = (float*)p;  p += NS * sizeof(float);

    u16* Wb1 = Wb;
    u16* Wb2 = Wb + (size_t)DD * DD;
    u16* Wb3 = Wb + (size_t)2 * DD * DD;
    u16* Wb4 = Wb + (size_t)3 * DD * DD;

    conv_f2bf<<<1024, 256, 0, stream>>>(W1, Wb1);
    conv_f2bf<<<1024, 256, 0, stream>>>(W2, Wb2);
    conv_f2bf<<<1024, 256, 0, stream>>>(W3, Wb3);
    conv_f2bf<<<1024, 256, 0, stream>>>(W4, Wb4);
    hipMemsetAsync(Sr, 0, 4 * NS * sizeof(float), stream);  // Sr and Sc contiguous

    // ---- row view projection: Hr = H ----
    conv_cat<<<16384, 256, 0, stream>>>(ta, tb, Z);
    gemm_bt<0><<<dim3(8, 128), 256, 0, stream>>>(Z, Wb1, b1, T);   // Z free after
    gemm_bt<1><<<dim3(8, 128), 256, 0, stream>>>(T, Wb2, b2, H);
    normalize_kernel<<<16384, 256, 0, stream>>>(H);
    diag_kernel<<<8192, 256, 0, stream>>>(H, gr);

    // ---- col view projection: Hc = Z (reuses freed buffer) ----
    conv_col<<<16384, 256, 0, stream>>>(ta, tb, Z);
    gemm_bt<0><<<dim3(8, 128), 256, 0, stream>>>(Z, Wb3, b3, T);
    gemm_bt<1><<<dim3(8, 128), 256, 0, stream>>>(T, Wb4, b4, Z);
    normalize_kernel<<<16384, 256, 0, stream>>>(Z);
    diag_kernel<<<8192, 256, 0, stream>>>(Z, gc);

    // ---- both Grams in one dispatch (4160 blocks) ----
    gram256<<<dim3(65, 64), 512, 0, stream>>>(H, Z, Sr);

    final_kernel<<<1, 256, 0, stream>>>(Sr, Sc, gr, gc, wr, out);
}

// Round 10
// 1298.868 us; speedup vs baseline: 1.0772x; 1.0772x over previous
//
#include <hip/hip_runtime.h>
#include <stdint.h>

// ---------------------------------------------------------------------------
// TContrastive: GRACE InfoNCE loss.
//   loss_view = (1/2N) sum_i log(S_i - e^2) - (2/N) sum_i g12_i
// where S = row sums of exp(2 * M M^T), M = [n1; n2] row-normalized (16384x1024).
// Heavy GEMMs in bf16 MFMA, fp32 accumulate. tau = 0.5.
// R1: Gram symmetry — triangle tiles only; off-diag adds row+col exp-sums.
// R2-R7 lessons:
//   - 256^2-tile variants (128KB LDS) run at 1 block/CU: all 8 waves stall
//     together at the staging gate; CU idles. Schedule surgery inside one
//     lockstep block (4-phase, 8-phase, counted-vmcnt) regressed or was flat.
//   - SQ_LDS_BANK_CONFLICT was the 16x16 fragment's 16-lane read pattern;
//     32x32x16 reads measure ZERO conflicts (R7). But conflicts were not on
//     the critical path (R7 slower despite 0).
//   - XCD chunk swizzle hurt (FETCH 314->488MB). Reverted.
// R8: gram back to multi-block residency (m97 regime): 128^2 tiles, 256 thr,
//     4 waves (2x2 of 64x64), 32x32x16 MFMA, 16KB single-buffer LDS,
//     __launch_bounds__(256,3) -> ~3 blocks/CU implicit overlap. Separate
//     dispatches per view (de-confound R7). fc GEMMs unchanged (R4).
// (R10 resubmission: R8/R9 benches hit GPUAcquisitionTimeout — no data.)
// ---------------------------------------------------------------------------

typedef unsigned short u16;
typedef __attribute__((ext_vector_type(8))) __bf16 bf16x8;
typedef __attribute__((ext_vector_type(4))) float f32x4;
typedef __attribute__((ext_vector_type(16))) float f32x16;

#define NS 8192       // samples per view half
#define DD 1024       // feature dim

__device__ __forceinline__ float bf2f(u16 u) {
    union { uint32_t i; float f; } v; v.i = ((uint32_t)u) << 16; return v.f;
}
__device__ __forceinline__ u16 f2bf(float f) {
    union { float f; uint32_t i; } v; v.f = f;
    return (u16)((v.i + 0x7FFFu + ((v.i >> 16) & 1u)) >> 16);   // RNE
}

// async global->LDS, 16B per lane. LDS dest must be wave-uniform-base + lane*16.
__device__ __forceinline__ void gload16(const u16* g, u16* l) {
    __builtin_amdgcn_global_load_lds(
        (__attribute__((address_space(1))) void*)(uintptr_t)(g),
        (__attribute__((address_space(3))) void*)(uintptr_t)(l), 16, 0, 0);
}

// ---------------- elementwise conversion kernels ----------------

__global__ __launch_bounds__(256) void conv_f2bf(const float* __restrict__ src,
                                                 u16* __restrict__ dst) {
    int i = (blockIdx.x * 256 + threadIdx.x) * 4;
    float4 v = *(const float4*)(src + i);
    ushort4 o;
    o.x = f2bf(v.x); o.y = f2bf(v.y); o.z = f2bf(v.z); o.w = f2bf(v.w);
    *(ushort4*)(dst + i) = o;
}

// Z = bf16([ta; tb]) row view (16384x1024), 16384 blocks
__global__ __launch_bounds__(256) void conv_cat(const float* __restrict__ a,
                                                const float* __restrict__ b,
                                                u16* __restrict__ Z) {
    size_t i = (size_t)(blockIdx.x * 256 + threadIdx.x) * 4;
    const size_t half = (size_t)NS * DD;
    const float* s = (i < half) ? (a + i) : (b + (i - half));
    float4 v = *(const float4*)s;
    ushort4 o;
    o.x = f2bf(v.x); o.y = f2bf(v.y); o.z = f2bf(v.z); o.w = f2bf(v.w);
    *(ushort4*)(Z + i) = o;
}

// column view: Z[i, b*32+a] = src[i, a*32+b]  (per-row 32x32 transpose)
__global__ __launch_bounds__(256) void conv_col(const float* __restrict__ a,
                                                const float* __restrict__ b,
                                                u16* __restrict__ Z) {
    size_t i = (size_t)(blockIdx.x * 256 + threadIdx.x) * 4;
    const size_t half = (size_t)NS * DD;
    const float* src; size_t o;
    if (i < half) { src = a; o = i; } else { src = b; o = i - half; }
    size_t row = o >> 10;
    int j = (int)(o & 1023);
    int aI = j & 31, bI = j >> 5;      // j = b*32 + a
    const float* rp = src + (row << 10);
    ushort4 ov;
    ov.x = f2bf(rp[aI * 32 + bI]);
    ov.y = f2bf(rp[(aI + 1) * 32 + bI]);
    ov.z = f2bf(rp[(aI + 2) * 32 + bI]);
    ov.w = f2bf(rp[(aI + 3) * 32 + bI]);
    *(ushort4*)(Z + i) = ov;
}

// ---------------- fc GEMM: C[m,n] = sum_k A[m,k] * B[n,k] (128^2 tile path)
// MODE 0: out = bf16(elu(C + bias))      (fc_a)
// MODE 1: out = bf16(C + bias)           (fc_b)
template <int MODE>
__global__ __launch_bounds__(256) void gemm_bt(const u16* A, const u16* B,
                                               const float* __restrict__ bias,
                                               u16* __restrict__ out) {
    __shared__ alignas(16) u16 As[128 * 32];
    __shared__ alignas(16) u16 Bs[128 * 32];
    const int tid = threadIdx.x;

    const int tm = blockIdx.y, tn = blockIdx.x;
    const size_t tileM = (size_t)tm * 128;
    const size_t tileN = (size_t)tn * 128;

    const int csw = ((tid & 3) ^ ((tid >> 4) & 3)) * 8;
    const u16* gA0 = A + (tileM + (tid >> 2)) * DD + csw;
    const u16* gA1 = gA0 + (size_t)64 * DD;
    const u16* gB0 = B + (tileN + (tid >> 2)) * DD + csw;
    const u16* gB1 = gB0 + (size_t)64 * DD;
    u16* lA0 = &As[tid * 8]; u16* lA1 = lA0 + 2048;
    u16* lB0 = &Bs[tid * 8]; u16* lB1 = lB0 + 2048;

    const int lane = tid & 63;
    const int wv = tid >> 6;
    const int wr = (wv >> 1) << 6;
    const int wc = (wv & 1) << 6;
    const int lr = lane & 15;
    const int lh = lane >> 4;
    const int sw = lh ^ ((lr >> 2) & 3);

    const u16* aBase = &As[(wr + lr) * 32 + sw * 8];
    const u16* bBase = &Bs[(wc + lr) * 32 + sw * 8];

    f32x4 acc[4][4];
#pragma unroll
    for (int i = 0; i < 4; i++)
#pragma unroll
        for (int j = 0; j < 4; j++) acc[i][j] = (f32x4)0.0f;

    for (int k0 = 0; k0 < DD; k0 += 32) {
        gload16(gA0 + k0, lA0);
        gload16(gA1 + k0, lA1);
        gload16(gB0 + k0, lB0);
        gload16(gB1 + k0, lB1);
        __syncthreads();
        bf16x8 af[4], bfr[4];
#pragma unroll
        for (int rt = 0; rt < 4; rt++) af[rt] = *(const bf16x8*)(aBase + rt * 512);
#pragma unroll
        for (int ct = 0; ct < 4; ct++) bfr[ct] = *(const bf16x8*)(bBase + ct * 512);
#pragma unroll
        for (int rt = 0; rt < 4; rt++)
#pragma unroll
            for (int ct = 0; ct < 4; ct++)
                acc[rt][ct] = __builtin_amdgcn_mfma_f32_16x16x32_bf16(
                    af[rt], bfr[ct], acc[rt][ct], 0, 0, 0);
        __syncthreads();
    }

    float bcol[4];
#pragma unroll
    for (int ct = 0; ct < 4; ct++) bcol[ct] = bias[tileN + wc + ct * 16 + lr];
#pragma unroll
    for (int rt = 0; rt < 4; rt++) {
#pragma unroll
        for (int r = 0; r < 4; r++) {
            size_t row = tileM + wr + rt * 16 + lh * 4 + r;
            u16* orow = out + row * DD + tileN + wc + lr;
#pragma unroll
            for (int ct = 0; ct < 4; ct++) {
                float v = acc[rt][ct][r] + bcol[ct];
                if (MODE == 0) v = v > 0.0f ? v : expm1f(v);
                orow[ct * 16] = f2bf(v);
            }
        }
    }
}

// ---------------- Gram kernel: 128^2 tiles, 4 waves, 32x32x16 MFMA ------
// m97 regime: 16KB single-buffer LDS, __syncthreads per K-tile, ~3 blocks/CU
// for implicit inter-block overlap of staging stalls. Triangle grid
// dim3(129, 64) = 8256 blocks = tile pairs (tm <= tn) of the 128-tile grid.
// S[row] += exp-row-sums; off-diag tiles also S[col] += exp-col-sums.
__global__ __launch_bounds__(256, 3) void gram128(const u16* __restrict__ H,
                                                  float* __restrict__ S) {
    __shared__ alignas(16) u16 As[128 * 32];
    __shared__ alignas(16) u16 Bs[128 * 32];
    const int tid = threadIdx.x;

    int x = blockIdx.x, y = blockIdx.y;      // x in [0,129), y in [0,64)
    int tm, tn;
    if (y + x < 128) { tm = y;       tn = y + x; }
    else             { tm = 127 - y; tn = x - 1; }
    const size_t rowA = (size_t)tm * 128;
    const size_t rowB = (size_t)tn * 128;

    // staging (same as fc): chunk c in [0,512), row=c>>2, slot=c&3; global col
    // pre-swizzled by (row>>2)&3 == (tid>>4)&3 (invariant under +64 rows).
    const int csw = ((tid & 3) ^ ((tid >> 4) & 3)) * 8;
    const u16* gA0 = H + (rowA + (tid >> 2)) * DD + csw;
    const u16* gA1 = gA0 + (size_t)64 * DD;
    const u16* gB0 = H + (rowB + (tid >> 2)) * DD + csw;
    const u16* gB1 = gB0 + (size_t)64 * DD;
    u16* lA0 = &As[tid * 8]; u16* lA1 = lA0 + 2048;
    u16* lB0 = &Bs[tid * 8]; u16* lB1 = lB0 + 2048;

    // MFMA indexing: 4 waves = 2x2, per-wave 64x64 = 2x2 tiles of 32x32.
    // Fragment (32x32x16): row = base + (lane&31), k = (lane>>5)*8 + j.
    // Stored slot for global slot g at row r is g ^ ((r>>2)&3); wr/wc/mt*32
    // vanish mod 4 after >>2, so q4 = ((lane&31)>>2)&3.  (R7-proven mapping.)
    const int lane = tid & 63;
    const int wv = tid >> 6;
    const int wr = (wv >> 1) * 64;           // 0 / 64
    const int wc = (wv & 1) * 64;            // 0 / 64
    const int c31 = lane & 31;
    const int hi  = lane >> 5;
    const int q4  = (c31 >> 2) & 3;
    const int o0  = (hi ^ q4) * 8;           // kk=0: global slot hi
    const int o1  = o0 ^ 16;                 // kk=1: global slot 2+hi
    const int aB = (wr + c31) * 32;
    const int bB = (wc + c31) * 32;

    f32x16 acc[2][2];
#pragma unroll
    for (int i = 0; i < 2; ++i)
#pragma unroll
        for (int j = 0; j < 2; ++j) acc[i][j] = (f32x16)0.0f;

    for (int k0 = 0; k0 < DD; k0 += 32) {
        gload16(gA0 + k0, lA0);
        gload16(gA1 + k0, lA1);
        gload16(gB0 + k0, lB0);
        gload16(gB1 + k0, lB1);
        __syncthreads();          // compiler drains vmcnt before s_barrier
        bf16x8 aF[2][2], bF[2][2];
#pragma unroll
        for (int mt = 0; mt < 2; ++mt) {
            aF[mt][0] = *(const bf16x8*)(&As[aB + mt * 1024 + o0]);
            aF[mt][1] = *(const bf16x8*)(&As[aB + mt * 1024 + o1]);
        }
#pragma unroll
        for (int nt = 0; nt < 2; ++nt) {
            bF[nt][0] = *(const bf16x8*)(&Bs[bB + nt * 1024 + o0]);
            bF[nt][1] = *(const bf16x8*)(&Bs[bB + nt * 1024 + o1]);
        }
#pragma unroll
        for (int mt = 0; mt < 2; ++mt)
#pragma unroll
            for (int nt = 0; nt < 2; ++nt)
#pragma unroll
                for (int kk = 0; kk < 2; ++kk)
                    acc[mt][nt] = __builtin_amdgcn_mfma_f32_32x32x16_bf16(
                        aF[mt][kk], bF[nt][kk], acc[mt][nt], 0, 0, 0);
        __syncthreads();
    }

    // epilogue: exp + row sums (always) + col sums (off-diag symmetry).
    // 32x32 C layout: col = lane&31, row = (j&3) + 8*(j>>2) + 4*(lane>>5).
    const bool offdiag = (tm != tn);
    float csum[2] = {0.f, 0.f};
#pragma unroll
    for (int mt = 0; mt < 2; ++mt) {
#pragma unroll
        for (int j = 0; j < 16; ++j) {
            float rs = 0.0f;
#pragma unroll
            for (int nt = 0; nt < 2; ++nt) {
                float e = __expf(2.0f * acc[mt][nt][j]);
                rs += e;
                csum[nt] += e;
            }
            rs += __shfl_xor(rs, 1);
            rs += __shfl_xor(rs, 2);
            rs += __shfl_xor(rs, 4);
            rs += __shfl_xor(rs, 8);
            rs += __shfl_xor(rs, 16);
            if (c31 == 0) {
                size_t row = rowA + wr + mt * 32 + (j & 3) + 8 * (j >> 2) + 4 * hi;
                atomicAdd(&S[row], rs);
            }
        }
    }
    if (offdiag) {
#pragma unroll
        for (int nt = 0; nt < 2; ++nt) {
            float cs = csum[nt];
            cs += __shfl_xor(cs, 32);      // merge the two row-halves
            if (hi == 0) {
                size_t col = rowB + wc + nt * 32 + c31;
                atomicAdd(&S[col], cs);
            }
        }
    }
}

// row-normalize bf16 matrix in place (one block per row of 1024)
__global__ __launch_bounds__(256) void normalize_kernel(u16* M) {
    __shared__ float red[4];
    const int tid = threadIdx.x;
    u16* row = M + ((size_t)blockIdx.x << 10);
    ushort4 v = ((const ushort4*)row)[tid];
    float x0 = bf2f(v.x), x1 = bf2f(v.y), x2 = bf2f(v.z), x3 = bf2f(v.w);
    float s = x0 * x0 + x1 * x1 + x2 * x2 + x3 * x3;
#pragma unroll
    for (int m = 1; m < 64; m <<= 1) s += __shfl_xor(s, m);
    if ((tid & 63) == 0) red[tid >> 6] = s;
    __syncthreads();
    float inv = rsqrtf(red[0] + red[1] + red[2] + red[3]);
    ushort4 o;
    o.x = f2bf(x0 * inv); o.y = f2bf(x1 * inv);
    o.z = f2bf(x2 * inv); o.w = f2bf(x3 * inv);
    ((ushort4*)row)[tid] = o;
}

// g12[i] = dot(M[i], M[i+NS])  (one block per i)
__global__ __launch_bounds__(256) void diag_kernel(const u16* M, float* g12) {
    __shared__ float red[4];
    const int tid = threadIdx.x;
    const u16* r1 = M + ((size_t)blockIdx.x << 10);
    const u16* r2 = r1 + ((size_t)NS << 10);
    ushort4 a = ((const ushort4*)r1)[tid];
    ushort4 b = ((const ushort4*)r2)[tid];
    float s = bf2f(a.x) * bf2f(b.x) + bf2f(a.y) * bf2f(b.y) +
              bf2f(a.z) * bf2f(b.z) + bf2f(a.w) * bf2f(b.w);
#pragma unroll
    for (int m = 1; m < 64; m <<= 1) s += __shfl_xor(s, m);
    if ((tid & 63) == 0) red[tid >> 6] = s;
    __syncthreads();
    if (tid == 0) g12[blockIdx.x] = red[0] + red[1] + red[2] + red[3];
}

__global__ __launch_bounds__(256) void final_kernel(const float* Sr, const float* Sc,
                                                    const float* gr, const float* gc,
                                                    const float* w_r1, float* out) {
    __shared__ float red[16];
    const float E2 = 7.389056098930650f;  // exp(1/tau), tau=0.5
    float a = 0.f, b = 0.f, c = 0.f, d = 0.f;
    for (int i = threadIdx.x; i < 2 * NS; i += 256) {
        a += logf(Sr[i] - E2);
        b += logf(Sc[i] - E2);
    }
    for (int i = threadIdx.x; i < NS; i += 256) {
        c += gr[i];
        d += gc[i];
    }
#pragma unroll
    for (int m = 1; m < 64; m <<= 1) {
        a += __shfl_xor(a, m); b += __shfl_xor(b, m);
        c += __shfl_xor(c, m); d += __shfl_xor(d, m);
    }
    int w = threadIdx.x >> 6;
    if ((threadIdx.x & 63) == 0) {
        red[w] = a; red[4 + w] = b; red[8 + w] = c; red[12 + w] = d;
    }
    __syncthreads();
    if (threadIdx.x == 0) {
        a = red[0] + red[1] + red[2] + red[3];
        b = red[4] + red[5] + red[6] + red[7];
        c = red[8] + red[9] + red[10] + red[11];
        d = red[12] + red[13] + red[14] + red[15];
        float lr = a / (2.0f * NS) - 2.0f * c / NS;
        float lc = b / (2.0f * NS) - 2.0f * d / NS;
        float w0 = w_r1[0];
        w0 = fminf(fmaxf(w0, 0.0f), 1.0f);
        out[0] = w0 * lr + (1.0f - w0) * lc;
    }
}

extern "C" void kernel_launch(void* const* d_in, const int* in_sizes, int n_in,
                              void* d_out, int out_size, void* d_ws, size_t ws_size,
                              hipStream_t stream) {
    const float* ta = (const float*)d_in[0];
    const float* tb = (const float*)d_in[1];
    const float* W1 = (const float*)d_in[2];
    const float* b1 = (const float*)d_in[3];
    const float* W2 = (const float*)d_in[4];
    const float* b2 = (const float*)d_in[5];
    const float* W3 = (const float*)d_in[6];
    const float* b3 = (const float*)d_in[7];
    const float* W4 = (const float*)d_in[8];
    const float* b4 = (const float*)d_in[9];
    const float* wr = (const float*)d_in[10];
    float* out = (float*)d_out;

    char* p = (char*)d_ws;
    const size_t MAT = (size_t)2 * NS * DD * sizeof(u16);  // 33.5 MB
    u16* Z = (u16*)p;  p += MAT;
    u16* T = (u16*)p;  p += MAT;
    u16* H = (u16*)p;  p += MAT;
    u16* Wb = (u16*)p; p += (size_t)4 * DD * DD * sizeof(u16);
    float* Sr = (float*)p;  p += 2 * NS * sizeof(float);
    float* Sc = (float*)p;  p += 2 * NS * sizeof(float);
    float* gr = (float*)p;  p += NS * sizeof(float);
    float* gc = (float*)p;  p += NS * sizeof(float);

    u16* Wb1 = Wb;
    u16* Wb2 = Wb + (size_t)DD * DD;
    u16* Wb3 = Wb + (size_t)2 * DD * DD;
    u16* Wb4 = Wb + (size_t)3 * DD * DD;

    conv_f2bf<<<1024, 256, 0, stream>>>(W1, Wb1);
    conv_f2bf<<<1024, 256, 0, stream>>>(W2, Wb2);
    conv_f2bf<<<1024, 256, 0, stream>>>(W3, Wb3);
    conv_f2bf<<<1024, 256, 0, stream>>>(W4, Wb4);
    hipMemsetAsync(Sr, 0, 4 * NS * sizeof(float), stream);  // Sr and Sc contiguous

    // ---- row view ----
    conv_cat<<<16384, 256, 0, stream>>>(ta, tb, Z);
    gemm_bt<0><<<dim3(8, 128), 256, 0, stream>>>(Z, Wb1, b1, T);
    gemm_bt<1><<<dim3(8, 128), 256, 0, stream>>>(T, Wb2, b2, H);
    normalize_kernel<<<16384, 256, 0, stream>>>(H);
    diag_kernel<<<8192, 256, 0, stream>>>(H, gr);
    gram128<<<dim3(129, 64), 256, 0, stream>>>(H, Sr);

    // ---- column view ----
    conv_col<<<16384, 256, 0, stream>>>(ta, tb, Z);
    gemm_bt<0><<<dim3(8, 128), 256, 0, stream>>>(Z, Wb3, b3, T);
    gemm_bt<1><<<dim3(8, 128), 256, 0, stream>>>(T, Wb4, b4, H);
    normalize_kernel<<<16384, 256, 0, stream>>>(H);
    diag_kernel<<<8192, 256, 0, stream>>>(H, gc);
    gram128<<<dim3(129, 64), 256, 0, stream>>>(H, Sc);

    final_kernel<<<1, 256, 0, stream>>>(Sr, Sc, gr, gc, wr, out);
}